// Round 1
// baseline (576.587 us; speedup 1.0000x reference)
//
#include <hip/hip_runtime.h>
#include <stdint.h>

// ---- JAX PRNG path: 1 = jax_threefry_partitionable (modern default), 0 = legacy split-iota
#define JAX_PARTITIONABLE 1

#define SNUM 10
#define NBATCH 4
#define NCLS 4
#define HH 512
#define WW 512
#define IMG (HH*WW)                   // 262144
#define NPIX (SNUM*NBATCH*IMG)        // 10485760
#define GUMTOT ((uint32_t)NPIX*NCLS)  // 41943040
#define HALFG (GUMTOT/2u)             // 20971520
#define WPI (IMG/32)                  // 8192 32-bit words per 512x512 image

__device__ __forceinline__ uint32_t rotl32(uint32_t x, int r) {
  return (x << r) | (x >> (32 - r));
}

// Threefry-2x32, key = (0, 42)  [jax.random.key(42)]
__device__ __forceinline__ void tf2x32(uint32_t x0, uint32_t x1,
                                       uint32_t& o0, uint32_t& o1) {
  const uint32_t k0 = 0u, k1 = 42u;
  const uint32_t k2 = k0 ^ k1 ^ 0x1BD11BDAu;
  x0 += k0; x1 += k1;
#define TFR(r) { x0 += x1; x1 = rotl32(x1, (r)); x1 ^= x0; }
  TFR(13) TFR(15) TFR(26) TFR(6)
  x0 += k1; x1 += k2 + 1u;
  TFR(17) TFR(29) TFR(16) TFR(24)
  x0 += k2; x1 += k0 + 2u;
  TFR(13) TFR(15) TFR(26) TFR(6)
  x0 += k0; x1 += k1 + 3u;
  TFR(17) TFR(29) TFR(16) TFR(24)
  x0 += k1; x1 += k2 + 4u;
  TFR(13) TFR(15) TFR(26) TFR(6)
  x0 += k2; x1 += k0 + 5u;
#undef TFR
  o0 = x0; o1 = x1;
}

// JAX uniform(minval=tiny, maxval=1) bit-exact mapping for f32
__device__ __forceinline__ float u01(uint32_t bits) {
  float f = __uint_as_float((bits >> 9) | 0x3f800000u) - 1.0f;
  const float tiny = 1.17549435e-38f;
  f = f + tiny;            // (maxval-minval) rounds to 1.0f in f32, so *1 + tiny
  return fmaxf(tiny, f);
}

__device__ __forceinline__ uint32_t gum_bits(uint32_t g) {
#if JAX_PARTITIONABLE
  uint32_t y0, y1;
  tf2x32(0u, g, y0, y1);      // counts = (hi32, lo32) of 64-bit flat index
  return y0 ^ y1;
#else
  uint32_t y0, y1;
  uint32_t j = (g < HALFG) ? g : (g - HALFG);
  tf2x32(j, j + HALFG, y0, y1);
  return (g < HALFG) ? y0 : y1;
#endif
}

// ---------------- Kernel A: categorical sampling ----------------
// One thread per 4 consecutive pixels (same row). Writes 2-bit packed classes.
__global__ __launch_bounds__(256) void k_sample(const float* __restrict__ preds,
                                                uint8_t* __restrict__ packed,
                                                float* __restrict__ acc) {
  int64_t t = (int64_t)blockIdx.x * blockDim.x + threadIdx.x;
  if (t == 0) acc[0] = 0.0f;   // zero the loss accumulator (ws is poisoned)
  const int64_t nthr = NPIX / 4;
  if (t >= nthr) return;
  int64_t p0 = t * 4;                 // flat pixel index over (s, n, h, w)
  int sn = (int)(p0 >> 18);           // = s*4 + n
  int n  = sn & 3;
  int pix = (int)(p0 & (IMG - 1));
  int h = pix >> 9;
  int w = pix & 511;

  float lg[NCLS][4];
#pragma unroll
  for (int c = 0; c < NCLS; ++c) {
    const float4 v = *reinterpret_cast<const float4*>(
        preds + ((((int64_t)(n * NCLS + c)) * HH + h) * WW + w));
    lg[c][0] = logf(v.x + 1e-16f);
    lg[c][1] = logf(v.y + 1e-16f);
    lg[c][2] = logf(v.z + 1e-16f);
    lg[c][3] = logf(v.w + 1e-16f);
  }

  uint32_t byte = 0;
#pragma unroll
  for (int j = 0; j < 4; ++j) {
    float best = -__builtin_inff();
    int bc = 0;
#pragma unroll
    for (int c = 0; c < NCLS; ++c) {
      uint32_t g = (uint32_t)(p0 + j) * 4u + (uint32_t)c;  // flat idx in (10,4,512,512,4)
      float u = u01(gum_bits(g));
      float gum = -logf(-logf(u));
      float sc = gum + lg[c][j];
      if (sc > best) { best = sc; bc = c; }   // strict > == jnp.argmax first-max
    }
    byte |= (uint32_t)bc << (2 * j);
  }
  packed[t] = (uint8_t)byte;
}

// ---------------- Kernel B: seed + flood fill + reward sum ----------------
// One workgroup per (image-sample, fg class): 40 * 3 = 120 blocks.
__global__ __launch_bounds__(256) void k_conn(const float* __restrict__ preds,
                                              const uint8_t* __restrict__ packed,
                                              float* __restrict__ acc,
                                              int* __restrict__ gflags) {
  __shared__ uint32_t fg[WPI];    // 32 KB
  __shared__ uint32_t fil[WPI];   // 32 KB  (total exactly 64 KB static LDS)
  const int tid = threadIdx.x;
  const int prob = blockIdx.x;
  const int sn = prob % 40;       // = s*4 + n
  const int k  = 1 + prob / 40;   // fg class 1..3
  const int n  = sn & 3;
  int* gch = gflags + prob;       // per-block global "changed" flag

  // Build fg bitmask from packed classes
  const uint64_t* p64 = reinterpret_cast<const uint64_t*>(packed);
  for (int wi = tid; wi < WPI; wi += 256) {
    uint64_t v = p64[(int64_t)sn * WPI + wi];   // 32 pixels, 2 bits each
    uint32_t m = 0;
#pragma unroll
    for (int j = 0; j < 32; ++j)
      m |= ((((uint32_t)(v >> (2 * j))) & 3u) == (uint32_t)k) ? (1u << j) : 0u;
    fg[wi] = m;
    fil[wi] = 0u;
  }
  __syncthreads();

  // 5x5 neighbor-count argmax with first-flat-index tie-break.
  // key = (count << 18) | (0x3FFFF - flatidx); max-key == (max count, min idx).
  uint32_t lbest = 0;
  for (int wi = tid; wi < WPI; wi += 256) {
    uint32_t cw = fg[wi];
    if (!cw) continue;
    int row = wi >> 4, col = wi & 15;
    uint64_t rb[5];
#pragma unroll
    for (int d = 0; d < 5; ++d) {
      int rr = row + d - 2;
      if (rr < 0 || rr >= HH) { rb[d] = 0; continue; }
      int base = (rr << 4) + col;
      uint32_t le = (col > 0)  ? fg[base - 1] : 0u;
      uint32_t cu = fg[base];
      uint32_t ri = (col < 15) ? fg[base + 1] : 0u;
      rb[d] = ((uint64_t)(ri & 7u) << 34) | ((uint64_t)cu << 2) | (uint64_t)(le >> 30);
    }
    uint32_t bits = cw;
    while (bits) {
      int j = __ffs(bits) - 1;
      bits &= bits - 1;
      int cnt = 0;
#pragma unroll
      for (int d = 0; d < 5; ++d)
        cnt += __popc((uint32_t)(rb[d] >> j) & 0x1fu);
      uint32_t key = ((uint32_t)cnt << 18) | (0x3FFFFu - (uint32_t)(wi * 32 + j));
      lbest = lbest > key ? lbest : key;
    }
  }
  atomicMax(&fil[0], lbest);      // fil[] is all-zero: reuse word 0 as the reducer
  __syncthreads();
  const uint32_t bkey = fil[0];
  const bool active = (bkey >> 18) != 0;   // has_fg
  __syncthreads();
  if (tid == 0) {
    fil[0] = 0u;
    if (active) {
      uint32_t seed = 0x3FFFFu - (bkey & 0x3FFFFu);
      fil[seed >> 5] = fil[seed >> 5] | (1u << (seed & 31));
    }
  }
  __syncthreads();

  // Flood fill: word-parallel 8-connected dilation to fixed point (monotone)
  while (true) {
    if (tid == 0) *gch = 0;
    __syncthreads();
    if (active) {
      int lc = 0;
      for (int wi = tid; wi < WPI; wi += 256) {
        uint32_t fgw = fg[wi];
        if (!fgw) continue;
        int row = wi >> 4, col = wi & 15;
        uint32_t a3 = 0;
#pragma unroll
        for (int d = -1; d <= 1; ++d) {
          int rr = row + d;
          if (rr < 0 || rr >= HH) continue;
          int base = (rr << 4) + col;
          uint32_t le = (col > 0)  ? fil[base - 1] : 0u;
          uint32_t cu = fil[base];
          uint32_t ri = (col < 15) ? fil[base + 1] : 0u;
          a3 |= cu | ((cu << 1) | (le >> 31)) | ((cu >> 1) | (ri << 31));
        }
        uint32_t nw = fgw & a3;
        uint32_t old = fil[wi];
        if (nw & ~old) { fil[wi] = old | nw; lc = 1; }
      }
      if (lc) *gch = 1;
    }
    __syncthreads();
    if (*gch == 0) break;
  }

  // Sum log(preds[n,k,h,w] + eps) over fill pixels (rewards == fill mask)
  float local = 0.0f;
  if (active) {
    for (int wi = tid; wi < WPI; wi += 256) {
      uint32_t bits = fil[wi];
      while (bits) {
        int j = __ffs(bits) - 1;
        bits &= bits - 1;
        int pix = wi * 32 + j;
        int h = pix >> 9, w2 = pix & 511;
        local += logf(preds[((((int64_t)n) * NCLS + k) * HH + h) * WW + w2] + 1e-16f);
      }
    }
  }
#pragma unroll
  for (int off = 32; off > 0; off >>= 1)
    local += __shfl_down(local, off, 64);
  if ((tid & 63) == 0 && local != 0.0f)
    atomicAdd(acc, local);
}

// ---------------- Kernel C: finalize ----------------
__global__ void k_final(const float* __restrict__ acc, float* __restrict__ out) {
  out[0] = -acc[0] / 10485760.0f;
}

extern "C" void kernel_launch(void* const* d_in, const int* in_sizes, int n_in,
                              void* d_out, int out_size, void* d_ws, size_t ws_size,
                              hipStream_t stream) {
  const float* preds = (const float*)d_in[0];
  float* out = (float*)d_out;
  // ws layout: [0..3] float acc | [64..543] 120 int changed-flags | [4096..] packed classes
  float* acc = (float*)d_ws;
  int* gflags = (int*)((char*)d_ws + 64);
  uint8_t* packed = (uint8_t*)d_ws + 4096;

  const int64_t nthrA = NPIX / 4;                 // 2,621,440
  const int grdA = (int)((nthrA + 255) / 256);    // 10,240 blocks
  k_sample<<<grdA, 256, 0, stream>>>(preds, packed, acc);
  k_conn<<<120, 256, 0, stream>>>(preds, packed, acc, gflags);
  k_final<<<1, 1, 0, stream>>>(acc, out);
}

// Round 2
// 241.395 us; speedup vs baseline: 2.3886x; 2.3886x over previous
//
#include <hip/hip_runtime.h>
#include <stdint.h>

// ---- JAX PRNG path: 1 = jax_threefry_partitionable (modern default), 0 = legacy split-iota
#define JAX_PARTITIONABLE 1

#define SNUM 10
#define NBATCH 4
#define NCLS 4
#define HH 512
#define WW 512
#define IMG (HH*WW)                   // 262144
#define NPIX (SNUM*NBATCH*IMG)        // 10485760
#define GUMTOT ((uint32_t)NPIX*NCLS)  // 41943040
#define HALFG (GUMTOT/2u)             // 20971520
#define WPI (IMG/32)                  // 8192 32-bit words per 512x512 image
#define QCAP 3584                     // BFS queue entries (words); component words << this

__device__ __forceinline__ uint32_t rotl32(uint32_t x, int r) {
  return (x << r) | (x >> (32 - r));
}

// Threefry-2x32, key = (0, 42)  [jax.random.key(42)]
__device__ __forceinline__ void tf2x32(uint32_t x0, uint32_t x1,
                                       uint32_t& o0, uint32_t& o1) {
  const uint32_t k0 = 0u, k1 = 42u;
  const uint32_t k2 = k0 ^ k1 ^ 0x1BD11BDAu;
  x0 += k0; x1 += k1;
#define TFR(r) { x0 += x1; x1 = rotl32(x1, (r)); x1 ^= x0; }
  TFR(13) TFR(15) TFR(26) TFR(6)
  x0 += k1; x1 += k2 + 1u;
  TFR(17) TFR(29) TFR(16) TFR(24)
  x0 += k2; x1 += k0 + 2u;
  TFR(13) TFR(15) TFR(26) TFR(6)
  x0 += k0; x1 += k1 + 3u;
  TFR(17) TFR(29) TFR(16) TFR(24)
  x0 += k1; x1 += k2 + 4u;
  TFR(13) TFR(15) TFR(26) TFR(6)
  x0 += k2; x1 += k0 + 5u;
#undef TFR
  o0 = x0; o1 = x1;
}

// JAX uniform(minval=tiny, maxval=1) bit-exact mapping for f32
__device__ __forceinline__ float u01(uint32_t bits) {
  float f = __uint_as_float((bits >> 9) | 0x3f800000u) - 1.0f;
  const float tiny = 1.17549435e-38f;
  f = f + tiny;
  return fmaxf(tiny, f);
}

__device__ __forceinline__ uint32_t gum_bits(uint32_t g) {
#if JAX_PARTITIONABLE
  uint32_t y0, y1;
  tf2x32(0u, g, y0, y1);
  return y0 ^ y1;
#else
  uint32_t y0, y1;
  uint32_t j = (g < HALFG) ? g : (g - HALFG);
  tf2x32(j, j + HALFG, y0, y1);
  return (g < HALFG) ? y0 : y1;
#endif
}

// ---------------- Kernel A: categorical sampling (bit-exact, unchanged) ----------------
__global__ __launch_bounds__(256) void k_sample(const float* __restrict__ preds,
                                                uint8_t* __restrict__ packed,
                                                float* __restrict__ acc) {
  int64_t t = (int64_t)blockIdx.x * blockDim.x + threadIdx.x;
  if (t == 0) acc[0] = 0.0f;
  const int64_t nthr = NPIX / 4;
  if (t >= nthr) return;
  int64_t p0 = t * 4;
  int sn = (int)(p0 >> 18);
  int n  = sn & 3;
  int pix = (int)(p0 & (IMG - 1));
  int h = pix >> 9;
  int w = pix & 511;

  float lg[NCLS][4];
#pragma unroll
  for (int c = 0; c < NCLS; ++c) {
    const float4 v = *reinterpret_cast<const float4*>(
        preds + ((((int64_t)(n * NCLS + c)) * HH + h) * WW + w));
    lg[c][0] = logf(v.x + 1e-16f);
    lg[c][1] = logf(v.y + 1e-16f);
    lg[c][2] = logf(v.z + 1e-16f);
    lg[c][3] = logf(v.w + 1e-16f);
  }

  uint32_t byte = 0;
#pragma unroll
  for (int j = 0; j < 4; ++j) {
    float best = -__builtin_inff();
    int bc = 0;
#pragma unroll
    for (int c = 0; c < NCLS; ++c) {
      uint32_t g = (uint32_t)(p0 + j) * 4u + (uint32_t)c;
      float u = u01(gum_bits(g));
      float gum = -logf(-logf(u));
      float sc = gum + lg[c][j];
      if (sc > best) { best = sc; bc = c; }
    }
    byte |= (uint32_t)bc << (2 * j);
  }
  packed[t] = (uint8_t)byte;
}

// ---- helpers for word-level BFS flood fill ----

// bits of all maximal runs of m that intersect s (requires s subset of m)
__device__ __forceinline__ uint32_t runmask(uint32_t m, uint32_t s) {
  uint32_t out = 0;
  while (s) {
    int j = __ffs(s) - 1;
    uint32_t bj = 1u << j;
    uint32_t up = ((m + bj) ^ m) & m;                       // j .. top of run
    uint32_t rm = __brev(m);
    uint32_t rbj = 1u << (31 - j);
    uint32_t dn = __brev(((rm + rbj) ^ rm) & rm);           // bottom .. j
    uint32_t run = up | dn;
    out |= run;
    s &= ~run;
  }
  return out;
}

// atomically claim `want` bits of fg[t]; extend claims to full horizontal runs
// within the word; push (word, claimed-bits) to the queue. Exactly-once per bit.
__device__ __forceinline__ void claimf(uint32_t* fg, uint32_t* qw, uint32_t* qb,
                                       uint32_t* qtail, uint32_t t, uint32_t want) {
  uint32_t old = atomicAnd(&fg[t], ~want);
  uint32_t nb = old & want;
  if (!nb) return;
  uint32_t ext = runmask(old, nb) & ~nb;
  if (ext) {
    uint32_t old2 = atomicAnd(&fg[t], ~ext);
    nb |= old2 & ext;
  }
  uint32_t slot = atomicAdd(qtail, 1u);
  if (slot < QCAP) { qw[slot] = t; qb[slot] = nb; }
}

// ---------------- Kernel B: seed + BFS flood fill + reward sum ----------------
// One workgroup per (image-sample, fg class): 40 * 3 = 120 blocks.
__global__ __launch_bounds__(256) void k_conn(const float* __restrict__ preds,
                                              const uint8_t* __restrict__ packed,
                                              float* __restrict__ acc) {
  __shared__ uint32_t fg[WPI];     // 32 KB, claimed bits get cleared during BFS
  __shared__ uint32_t qw[QCAP];    // 14 KB  queue: word index
  __shared__ uint32_t qb[QCAP];    // 14 KB  queue: claimed bits in that word
  __shared__ uint32_t skey;        // argmax reducer
  __shared__ uint32_t qtail;       // queue tail
  const int tid = threadIdx.x;
  const int prob = blockIdx.x;
  const int sn = prob % 40;        // = s*4 + n
  const int k  = 1 + prob / 40;    // fg class 1..3
  const int n  = sn & 3;

  if (tid == 0) { skey = 0u; qtail = 0u; }

  // Build fg bitmask from packed classes (bit-trick: field==k <=> 2-bit field of v^pat == 0)
  const uint64_t* p64 = reinterpret_cast<const uint64_t*>(packed);
  const uint64_t pat = (uint64_t)k * 0x5555555555555555ULL;
  for (int wi = tid; wi < WPI; wi += 256) {
    uint64_t v = p64[(int64_t)sn * WPI + wi] ^ pat;
    uint64_t tt = v | (v >> 1);
    uint64_t u = ~tt & 0x5555555555555555ULL;    // indicator at even bit positions
    u = (u ^ (u >> 1))  & 0x3333333333333333ULL; // compact even bits -> low 32
    u = (u ^ (u >> 2))  & 0x0F0F0F0F0F0F0F0FULL;
    u = (u ^ (u >> 4))  & 0x00FF00FF00FF00FFULL;
    u = (u ^ (u >> 8))  & 0x0000FFFF0000FFFFULL;
    u = (u ^ (u >> 16)) & 0x00000000FFFFFFFFULL;
    fg[wi] = (uint32_t)u;
  }
  __syncthreads();

  // 5x5 neighbor-count argmax with first-flat-index tie-break.
  // key = (count << 18) | (0x3FFFF - flatidx); max-key == (max count, min idx).
  uint32_t lbest = 0;
  for (int wi = tid; wi < WPI; wi += 256) {
    uint32_t cw = fg[wi];
    if (!cw) continue;
    int row = wi >> 4, col = wi & 15;
    uint64_t rb[5];
#pragma unroll
    for (int d = 0; d < 5; ++d) {
      int rr = row + d - 2;
      if (rr < 0 || rr >= HH) { rb[d] = 0; continue; }
      int base = (rr << 4) + col;
      uint32_t le = (col > 0)  ? fg[base - 1] : 0u;
      uint32_t cu = fg[base];
      uint32_t ri = (col < 15) ? fg[base + 1] : 0u;
      rb[d] = ((uint64_t)(ri & 7u) << 34) | ((uint64_t)cu << 2) | (uint64_t)(le >> 30);
    }
    uint32_t bits = cw;
    while (bits) {
      int j = __ffs(bits) - 1;
      bits &= bits - 1;
      int cnt = 0;
#pragma unroll
      for (int d = 0; d < 5; ++d)
        cnt += __popc((uint32_t)(rb[d] >> j) & 0x1fu);
      uint32_t key = ((uint32_t)cnt << 18) | (0x3FFFFu - (uint32_t)(wi * 32 + j));
      lbest = lbest > key ? lbest : key;
    }
  }
  atomicMax(&skey, lbest);
  __syncthreads();
  const uint32_t bkey = skey;

  // BFS flood fill by wave 0 only (no barriers needed inside: wave lockstep).
  if ((bkey >> 18) != 0u && tid < 64) {
    uint32_t seed = 0x3FFFFu - (bkey & 0x3FFFFu);
    // all 64 lanes issue the claim; the atomic guarantees exactly one push
    claimf(fg, qw, qb, &qtail, seed >> 5, 1u << (seed & 31));
    uint32_t head = 0;
    while (true) {
      uint32_t tail = atomicAdd(&qtail, 0u);
      if (tail > QCAP) tail = QCAP;
      if (head >= tail) break;
      for (uint32_t i = head + (uint32_t)tid; i < tail; i += 64) {
        uint32_t w = qw[i], got = qb[i];
        int row = (int)(w >> 4), cb = (int)(w & 15);
        uint32_t spread = got | (got << 1) | (got >> 1);
        bool lo = (got & 1u) != 0u, hi = (got >> 31) != 0u;
        if (row > 0) {
          claimf(fg, qw, qb, &qtail, w - 16, spread);
          if (cb > 0 && lo)  claimf(fg, qw, qb, &qtail, w - 17, 0x80000000u);
          if (cb < 15 && hi) claimf(fg, qw, qb, &qtail, w - 15, 1u);
        }
        if (row < HH - 1) {
          claimf(fg, qw, qb, &qtail, w + 16, spread);
          if (cb > 0 && lo)  claimf(fg, qw, qb, &qtail, w + 15, 0x80000000u);
          if (cb < 15 && hi) claimf(fg, qw, qb, &qtail, w + 17, 1u);
        }
        if (cb > 0 && lo)  claimf(fg, qw, qb, &qtail, w - 1, 0x80000000u);
        if (cb < 15 && hi) claimf(fg, qw, qb, &qtail, w + 1, 1u);
      }
      head = tail;
    }
  }
  __syncthreads();

  // rewards == fill mask == union of queue entries (disjoint bits, no double count)
  uint32_t tot = qtail;
  if (tot > QCAP) tot = QCAP;
  float local = 0.0f;
  const float* chan = preds + (((int64_t)n) * NCLS + k) * (int64_t)IMG;
  for (uint32_t i = (uint32_t)tid; i < tot; i += 256) {
    uint32_t w = qw[i], bits = qb[i];
    int row = (int)(w >> 4);
    int colb = (int)(w & 15) << 5;
    const float* rowp = chan + (int64_t)row * WW;
    while (bits) {
      int j = __ffs(bits) - 1;
      bits &= bits - 1;
      local += logf(rowp[colb + j] + 1e-16f);
    }
  }
#pragma unroll
  for (int off = 32; off > 0; off >>= 1)
    local += __shfl_down(local, off, 64);
  if ((tid & 63) == 0 && local != 0.0f)
    atomicAdd(acc, local);
}

// ---------------- Kernel C: finalize ----------------
__global__ void k_final(const float* __restrict__ acc, float* __restrict__ out) {
  out[0] = -acc[0] / 10485760.0f;
}

extern "C" void kernel_launch(void* const* d_in, const int* in_sizes, int n_in,
                              void* d_out, int out_size, void* d_ws, size_t ws_size,
                              hipStream_t stream) {
  const float* preds = (const float*)d_in[0];
  float* out = (float*)d_out;
  float* acc = (float*)d_ws;
  uint8_t* packed = (uint8_t*)d_ws + 4096;

  const int64_t nthrA = NPIX / 4;                 // 2,621,440
  const int grdA = (int)((nthrA + 255) / 256);    // 10,240 blocks
  k_sample<<<grdA, 256, 0, stream>>>(preds, packed, acc);
  k_conn<<<120, 256, 0, stream>>>(preds, packed, acc);
  k_final<<<1, 1, 0, stream>>>(acc, out);
}

// Round 4
// 218.774 us; speedup vs baseline: 2.6355x; 1.1034x over previous
//
#include <hip/hip_runtime.h>
#include <stdint.h>

// ---- JAX PRNG path: 1 = jax_threefry_partitionable (modern default), 0 = legacy split-iota
#define JAX_PARTITIONABLE 1

#define SNUM 10
#define NBATCH 4
#define NCLS 4
#define HH 512
#define WW 512
#define IMG (HH*WW)                   // 262144
#define NPIX (SNUM*NBATCH*IMG)        // 10485760
#define GUMTOT ((uint32_t)NPIX*NCLS)  // 41943040
#define HALFG (GUMTOT/2u)             // 20971520
#define WPI (IMG/32)                  // 8192 32-bit words per 512x512 image
#define QCAP 3584                     // BFS fallback queue entries

__device__ __forceinline__ uint32_t rotl32(uint32_t x, int r) {
  return (x << r) | (x >> (32 - r));
}

// Threefry-2x32, key = (0, 42)  [jax.random.key(42)]
__device__ __forceinline__ void tf2x32(uint32_t x0, uint32_t x1,
                                       uint32_t& o0, uint32_t& o1) {
  const uint32_t k0 = 0u, k1 = 42u;
  const uint32_t k2 = k0 ^ k1 ^ 0x1BD11BDAu;
  x0 += k0; x1 += k1;
#define TFR(r) { x0 += x1; x1 = rotl32(x1, (r)); x1 ^= x0; }
  TFR(13) TFR(15) TFR(26) TFR(6)
  x0 += k1; x1 += k2 + 1u;
  TFR(17) TFR(29) TFR(16) TFR(24)
  x0 += k2; x1 += k0 + 2u;
  TFR(13) TFR(15) TFR(26) TFR(6)
  x0 += k0; x1 += k1 + 3u;
  TFR(17) TFR(29) TFR(16) TFR(24)
  x0 += k1; x1 += k2 + 4u;
  TFR(13) TFR(15) TFR(26) TFR(6)
  x0 += k2; x1 += k0 + 5u;
#undef TFR
  o0 = x0; o1 = x1;
}

// JAX uniform(minval=tiny, maxval=1) bit-exact mapping for f32
__device__ __forceinline__ float u01(uint32_t bits) {
  float f = __uint_as_float((bits >> 9) | 0x3f800000u) - 1.0f;
  const float tiny = 1.17549435e-38f;
  f = f + tiny;
  return fmaxf(tiny, f);
}

__device__ __forceinline__ uint32_t gum_bits(uint32_t g) {
#if JAX_PARTITIONABLE
  uint32_t y0, y1;
  tf2x32(0u, g, y0, y1);
  return y0 ^ y1;
#else
  uint32_t y0, y1;
  uint32_t j = (g < HALFG) ? g : (g - HALFG);
  tf2x32(j, j + HALFG, y0, y1);
  return (g < HALFG) ? y0 : y1;
#endif
}

// ---------------- Kernel A: categorical sampling ----------------
// One thread per (n, 4-pixel group); loops over all 10 samples reusing preds.
// argmax_c[gumbel_c + log(p_c+eps)] == argmax_c (p_c+eps)/(-log u_c),
// compared via positive cross-multiplies (flips only at float near-ties).
__global__ __launch_bounds__(256) void k_sample(const float* __restrict__ preds,
                                                uint8_t* __restrict__ packed,
                                                float* __restrict__ acc) {
  int t = blockIdx.x * 256 + threadIdx.x;   // 262144 threads
  if (t == 0) acc[0] = 0.0f;
  const int n  = t >> 16;
  const int pg = t & 65535;
  const int pix = pg << 2;

  float pp[NCLS][4];
#pragma unroll
  for (int c = 0; c < NCLS; ++c) {
    const float4 v = *reinterpret_cast<const float4*>(
        preds + (((int64_t)(n * NCLS + c)) << 18) + pix);
    pp[c][0] = v.x + 1e-16f;
    pp[c][1] = v.y + 1e-16f;
    pp[c][2] = v.z + 1e-16f;
    pp[c][3] = v.w + 1e-16f;
  }

#pragma unroll 1     // keep the 10-sample loop rolled: 16 threefry bodies per iter stays in I$
  for (int s = 0; s < SNUM; ++s) {
    const uint32_t sn = (uint32_t)(s * NBATCH + n);
    const uint32_t gb = sn * 1048576u + ((uint32_t)pix << 2);  // flat idx in (10,4,512,512,4)
    uint32_t byte = 0;
#pragma unroll
    for (int j = 0; j < 4; ++j) {
      float bp = pp[0][j];
      float be = -__logf(u01(gum_bits(gb + (uint32_t)(j * 4))));
      int bc = 0;
#pragma unroll
      for (int c = 1; c < NCLS; ++c) {
        float ec = -__logf(u01(gum_bits(gb + (uint32_t)(j * 4 + c))));
        if (pp[c][j] * be > bp * ec) { bp = pp[c][j]; be = ec; bc = c; }
      }
      byte |= (uint32_t)bc << (2 * j);
    }
    packed[(int64_t)sn * 65536 + pg] = (uint8_t)byte;
  }
}

// ---- helpers for the BFS fallback (same as validated R2 code) ----

__device__ __forceinline__ uint32_t runmask(uint32_t m, uint32_t s) {
  uint32_t out = 0;
  while (s) {
    int j = __ffs(s) - 1;
    uint32_t bj = 1u << j;
    uint32_t up = ((m + bj) ^ m) & m;
    uint32_t rm = __brev(m);
    uint32_t rbj = 1u << (31 - j);
    uint32_t dn = __brev(((rm + rbj) ^ rm) & rm);
    uint32_t run = up | dn;
    out |= run;
    s &= ~run;
  }
  return out;
}

__device__ __forceinline__ void claimf(uint32_t* fg, uint32_t* qw, uint32_t* qb,
                                       uint32_t* qtail, uint32_t t, uint32_t want) {
  uint32_t old = atomicAnd(&fg[t], ~want);
  uint32_t nb = old & want;
  if (!nb) return;
  uint32_t ext = runmask(old, nb) & ~nb;
  if (ext) {
    uint32_t old2 = atomicAnd(&fg[t], ~ext);
    nb |= old2 & ext;
  }
  uint32_t slot = atomicAdd(qtail, 1u);
  if (slot < QCAP) { qw[slot] = t; qb[slot] = nb; }
}

// unconditional wave64 shuffles (all lanes execute; out-of-range = self-read per HIP)
__device__ __forceinline__ uint64_t shup64(uint64_t v) {
  uint32_t lo = __shfl_up((unsigned int)v, 1, 64);
  uint32_t hi = __shfl_up((unsigned int)(v >> 32), 1, 64);
  return ((uint64_t)hi << 32) | lo;
}
__device__ __forceinline__ uint64_t shdn64(uint64_t v) {
  uint32_t lo = __shfl_down((unsigned int)v, 1, 64);
  uint32_t hi = __shfl_down((unsigned int)(v >> 32), 1, 64);
  return ((uint64_t)hi << 32) | lo;
}

// ---------------- Kernel B: seed + windowed flood fill + reward sum ----------------
// One workgroup per (image-sample, fg class): 40 * 3 = 120 blocks.
__global__ __launch_bounds__(256) void k_conn(const float* __restrict__ preds,
                                              const uint8_t* __restrict__ packed,
                                              float* __restrict__ acc) {
  __shared__ uint32_t fg[WPI];     // 32 KB
  __shared__ uint32_t qw[QCAP];    // 14 KB (BFS fallback)
  __shared__ uint32_t qb[QCAP];    // 14 KB
  __shared__ uint32_t skey;
  __shared__ uint32_t qtail;
  const int tid = threadIdx.x;
  const int prob = blockIdx.x;
  const int sn = prob % 40;        // = s*4 + n
  const int k  = 1 + prob / 40;    // fg class 1..3
  const int n  = sn & 3;

  if (tid == 0) { skey = 0u; qtail = 0u; }

  // Build fg bitmask from packed classes
  const uint64_t* p64 = reinterpret_cast<const uint64_t*>(packed);
  const uint64_t pat = (uint64_t)k * 0x5555555555555555ULL;
  for (int wi = tid; wi < WPI; wi += 256) {
    uint64_t v = p64[(int64_t)sn * WPI + wi] ^ pat;
    uint64_t tt = v | (v >> 1);
    uint64_t u = ~tt & 0x5555555555555555ULL;
    u = (u ^ (u >> 1))  & 0x3333333333333333ULL;
    u = (u ^ (u >> 2))  & 0x0F0F0F0F0F0F0F0FULL;
    u = (u ^ (u >> 4))  & 0x00FF00FF00FF00FFULL;
    u = (u ^ (u >> 8))  & 0x0000FFFF0000FFFFULL;
    u = (u ^ (u >> 16)) & 0x00000000FFFFFFFFULL;
    fg[wi] = (uint32_t)u;
  }
  __syncthreads();

  // 5x5 neighbor-count argmax, first-flat-index tie-break.
  uint32_t lbest = 0;
  for (int wi = tid; wi < WPI; wi += 256) {
    uint32_t cw = fg[wi];
    if (!cw) continue;
    int row = wi >> 4, col = wi & 15;
    uint64_t rb[5];
#pragma unroll
    for (int d = 0; d < 5; ++d) {
      int rr = row + d - 2;
      if (rr < 0 || rr >= HH) { rb[d] = 0; continue; }
      int base = (rr << 4) + col;
      uint32_t le = (col > 0)  ? fg[base - 1] : 0u;
      uint32_t cu = fg[base];
      uint32_t ri = (col < 15) ? fg[base + 1] : 0u;
      rb[d] = ((uint64_t)(ri & 7u) << 34) | ((uint64_t)cu << 2) | (uint64_t)(le >> 30);
    }
    uint32_t bits = cw;
    while (bits) {
      int j = __ffs(bits) - 1;
      bits &= bits - 1;
      int cnt = 0;
#pragma unroll
      for (int d = 0; d < 5; ++d)
        cnt += __popc((uint32_t)(rb[d] >> j) & 0x1fu);
      uint32_t key = ((uint32_t)cnt << 18) | (0x3FFFFu - (uint32_t)(wi * 32 + j));
      lbest = lbest > key ? lbest : key;
    }
  }
  atomicMax(&skey, lbest);
  __syncthreads();
  const uint32_t bkey = skey;

  if (tid >= 64) return;               // waves 1-3 done (no further barriers)
  if ((bkey >> 18) == 0u) return;      // no fg anywhere -> reward 0

  const uint32_t seed = 0x3FFFFu - (bkey & 0x3FFFFu);
  const int sr = (int)(seed >> 9), sc = (int)(seed & 511);
  const float* chan = preds + (((int64_t)n) * NCLS + k) * (int64_t)IMG;
  float local = 0.0f;

  // ---- windowed register flood fill: 64 rows x 64 cols around the seed ----
  int r0 = sr - 31; if (r0 < 0) r0 = 0; if (r0 > HH - 64) r0 = HH - 64;
  int cl = (sc >> 5) - (((sc & 31) < 16) ? 1 : 0);
  if (cl < 0) cl = 0; if (cl > 14) cl = 14;
  const int ar = r0 + tid;                       // this lane's absolute row
  const uint64_t fgw = ((uint64_t)fg[(ar << 4) + cl + 1] << 32) | fg[(ar << 4) + cl];
  uint64_t fill = (ar == sr) ? (1ULL << (sc - (cl << 5))) : 0ULL;

  bool conv = false;
  for (int it = 0; it < 2048; ++it) {            // hard cap; non-convergence -> BFS
    uint64_t up = shup64(fill); if (tid == 0)  up = 0ULL;
    uint64_t dn = shdn64(fill); if (tid == 63) dn = 0ULL;
    uint64_t sp = fill | up | dn;
    uint64_t nf = (fgw & (sp | (sp << 1) | (sp >> 1))) | fill;
    bool ch = (nf != fill);
    fill = nf;
    if (__ballot(ch) == 0ULL) { conv = true; break; }
  }

  bool esc = !conv;
  if (fill) {
    if (tid == 0 && r0 > 0) esc = true;
    if (tid == 63 && r0 + 63 < HH - 1) esc = true;
    if ((fill & 1ULL) && cl > 0) esc = true;
    if ((fill >> 63) && cl < 14) esc = true;
  }

  if (__ballot(esc) == 0ULL) {
    // component fully inside the window: sum log(p+eps) over fill bits
    uint64_t bits = fill;
    const float* rowp = chan + (int64_t)ar * WW + (cl << 5);
    while (bits) {
      int j = __ffsll((unsigned long long)bits) - 1;
      bits &= bits - 1;
      local += logf(rowp[j] + 1e-16f);
    }
  } else {
    // ---- rare fallback: exact word-level BFS (fg untouched by window pass) ----
    claimf(fg, qw, qb, &qtail, seed >> 5, 1u << (seed & 31));
    uint32_t head = 0;
    while (true) {
      uint32_t tail = atomicAdd(&qtail, 0u);
      if (tail > QCAP) tail = QCAP;
      if (head >= tail) break;
      for (uint32_t i = head + (uint32_t)tid; i < tail; i += 64) {
        uint32_t w = qw[i], got = qb[i];
        int row = (int)(w >> 4), cb = (int)(w & 15);
        uint32_t spread = got | (got << 1) | (got >> 1);
        bool lo = (got & 1u) != 0u, hi = (got >> 31) != 0u;
        if (row > 0) {
          claimf(fg, qw, qb, &qtail, w - 16, spread);
          if (cb > 0 && lo)  claimf(fg, qw, qb, &qtail, w - 17, 0x80000000u);
          if (cb < 15 && hi) claimf(fg, qw, qb, &qtail, w - 15, 1u);
        }
        if (row < HH - 1) {
          claimf(fg, qw, qb, &qtail, w + 16, spread);
          if (cb > 0 && lo)  claimf(fg, qw, qb, &qtail, w + 15, 0x80000000u);
          if (cb < 15 && hi) claimf(fg, qw, qb, &qtail, w + 17, 1u);
        }
        if (cb > 0 && lo)  claimf(fg, qw, qb, &qtail, w - 1, 0x80000000u);
        if (cb < 15 && hi) claimf(fg, qw, qb, &qtail, w + 1, 1u);
      }
      head = tail;
    }
    uint32_t tot = qtail; if (tot > QCAP) tot = QCAP;
    for (uint32_t i = (uint32_t)tid; i < tot; i += 64) {
      uint32_t w = qw[i], bits = qb[i];
      int row = (int)(w >> 4);
      int colb = (int)(w & 15) << 5;
      const float* rowp = chan + (int64_t)row * WW;
      while (bits) {
        int j = __ffs(bits) - 1;
        bits &= bits - 1;
        local += logf(rowp[colb + j] + 1e-16f);
      }
    }
  }

#pragma unroll
  for (int off = 32; off > 0; off >>= 1)
    local += __shfl_down(local, off, 64);
  if (tid == 0 && local != 0.0f)
    atomicAdd(acc, local);
}

// ---------------- Kernel C: finalize ----------------
__global__ void k_final(const float* __restrict__ acc, float* __restrict__ out) {
  out[0] = -acc[0] / 10485760.0f;
}

extern "C" void kernel_launch(void* const* d_in, const int* in_sizes, int n_in,
                              void* d_out, int out_size, void* d_ws, size_t ws_size,
                              hipStream_t stream) {
  const float* preds = (const float*)d_in[0];
  float* out = (float*)d_out;
  float* acc = (float*)d_ws;
  uint8_t* packed = (uint8_t*)d_ws + 4096;

  k_sample<<<1024, 256, 0, stream>>>(preds, packed, acc);   // 262144 threads
  k_conn<<<120, 256, 0, stream>>>(preds, packed, acc);
  k_final<<<1, 1, 0, stream>>>(acc, out);
}

// Round 5
// 162.000 us; speedup vs baseline: 3.5592x; 1.3505x over previous
//
#include <hip/hip_runtime.h>
#include <stdint.h>

// ---- JAX PRNG path: 1 = jax_threefry_partitionable (modern default), 0 = legacy split-iota
#define JAX_PARTITIONABLE 1

#define SNUM 10
#define NBATCH 4
#define NCLS 4
#define HH 512
#define WW 512
#define IMG (HH*WW)                   // 262144
#define NPIX (SNUM*NBATCH*IMG)        // 10485760
#define GUMTOT ((uint32_t)NPIX*NCLS)  // 41943040
#define HALFG (GUMTOT/2u)             // 20971520
#define WPI (IMG/32)                  // 8192 32-bit words per 512x512 image
#define QCAP 3584                     // BFS fallback queue entries

#if __has_builtin(__builtin_amdgcn_alignbit)
__device__ __forceinline__ uint32_t rotl32(uint32_t x, int r) {
  return __builtin_amdgcn_alignbit(x, x, (uint32_t)(32 - r));  // v_alignbit_b32 = rotr
}
#else
__device__ __forceinline__ uint32_t rotl32(uint32_t x, int r) {
  return (x << r) | (x >> (32 - r));
}
#endif

// Threefry-2x32, key = (0, 42)  [jax.random.key(42)]
__device__ __forceinline__ void tf2x32(uint32_t x0, uint32_t x1,
                                       uint32_t& o0, uint32_t& o1) {
  const uint32_t k0 = 0u, k1 = 42u;
  const uint32_t k2 = k0 ^ k1 ^ 0x1BD11BDAu;
  x0 += k0; x1 += k1;
#define TFR(r) { x0 += x1; x1 = rotl32(x1, (r)); x1 ^= x0; }
  TFR(13) TFR(15) TFR(26) TFR(6)
  x0 += k1; x1 += k2 + 1u;
  TFR(17) TFR(29) TFR(16) TFR(24)
  x0 += k2; x1 += k0 + 2u;
  TFR(13) TFR(15) TFR(26) TFR(6)
  x0 += k0; x1 += k1 + 3u;
  TFR(17) TFR(29) TFR(16) TFR(24)
  x0 += k1; x1 += k2 + 4u;
  TFR(13) TFR(15) TFR(26) TFR(6)
  x0 += k2; x1 += k0 + 5u;
#undef TFR
  o0 = x0; o1 = x1;
}

// JAX uniform(minval=tiny, maxval=1) bit-exact mapping for f32
__device__ __forceinline__ float u01(uint32_t bits) {
  float f = __uint_as_float((bits >> 9) | 0x3f800000u) - 1.0f;
  const float tiny = 1.17549435e-38f;
  f = f + tiny;
  return fmaxf(tiny, f);
}

__device__ __forceinline__ uint32_t gum_bits(uint32_t g) {
#if JAX_PARTITIONABLE
  uint32_t y0, y1;
  tf2x32(0u, g, y0, y1);
  return y0 ^ y1;
#else
  uint32_t y0, y1;
  uint32_t j = (g < HALFG) ? g : (g - HALFG);
  tf2x32(j, j + HALFG, y0, y1);
  return (g < HALFG) ? y0 : y1;
#endif
}

// unpack: given 64-bit packed 2-bit classes XORed with k-pattern, return 32-bit
// mask of fields equal to k
__device__ __forceinline__ uint32_t unpack32(uint64_t v) {
  uint64_t tt = v | (v >> 1);
  uint64_t u = ~tt & 0x5555555555555555ULL;
  u = (u ^ (u >> 1))  & 0x3333333333333333ULL;
  u = (u ^ (u >> 2))  & 0x0F0F0F0F0F0F0F0FULL;
  u = (u ^ (u >> 4))  & 0x00FF00FF00FF00FFULL;
  u = (u ^ (u >> 8))  & 0x0000FFFF0000FFFFULL;
  u = (u ^ (u >> 16)) & 0x00000000FFFFFFFFULL;
  return (uint32_t)u;
}

// ---------------- Kernel A: categorical sampling ----------------
// One thread per (sample, image, 4-pixel group): 2,621,440 threads (R2 shape,
// 78% occupancy). argmax_c[gumbel_c + log(p_c+eps)] == argmax_c (p_c+eps)/(-log2 u_c)
// (ln2 scale cancels in the ratio), compared via positive cross-multiplies.
__global__ __launch_bounds__(256) void k_sample(const float* __restrict__ preds,
                                                uint8_t* __restrict__ packed,
                                                float* __restrict__ acc,
                                                uint32_t* __restrict__ gkey) {
  const int t = blockIdx.x * 256 + threadIdx.x;   // < 2,621,440
  if (t == 0) acc[0] = 0.0f;
  if (t < 120) gkey[t] = 0u;                      // zero the per-prob argmax keys
  const int sn = t >> 16;                         // s*4 + n
  const int n  = sn & 3;
  const int pg = t & 65535;
  const int pix = pg << 2;

  float pp[NCLS][4];
#pragma unroll
  for (int c = 0; c < NCLS; ++c) {
    const float4 v = *reinterpret_cast<const float4*>(
        preds + (((int64_t)(n * NCLS + c)) << 18) + pix);
    pp[c][0] = v.x + 1e-16f;
    pp[c][1] = v.y + 1e-16f;
    pp[c][2] = v.z + 1e-16f;
    pp[c][3] = v.w + 1e-16f;
  }

  const uint32_t gb = (uint32_t)sn * 1048576u + ((uint32_t)pix << 2);
  uint32_t byte = 0;
#pragma unroll
  for (int j = 0; j < 4; ++j) {
    float bp = pp[0][j];
    float be = -__log2f(u01(gum_bits(gb + (uint32_t)(j * 4))));
    int bc = 0;
#pragma unroll
    for (int c = 1; c < NCLS; ++c) {
      float ec = -__log2f(u01(gum_bits(gb + (uint32_t)(j * 4 + c))));
      if (pp[c][j] * be > bp * ec) { bp = pp[c][j]; be = ec; bc = c; }
    }
    byte |= (uint32_t)bc << (2 * j);
  }
  packed[t] = (uint8_t)byte;
}

// ---------------- Kernel B1: 5x5 neighbor-count argmax ----------------
// 1920 blocks = 120 probs x 16 row-slabs of 32 rows. LDS slab = 36 rows x 16 words.
__global__ __launch_bounds__(256) void k_argmax(const uint8_t* __restrict__ packed,
                                                uint32_t* __restrict__ gkey) {
  __shared__ uint32_t sfg[36 * 16];   // 2304 B
  __shared__ uint32_t skey;
  const int tid = threadIdx.x;
  const int b = blockIdx.x;
  const int prob = b >> 4;
  const int slab = b & 15;
  const int sn = prob % 40;
  const int k  = 1 + prob / 40;
  if (tid == 0) skey = 0u;

  const uint64_t* p64 = reinterpret_cast<const uint64_t*>(packed);
  const uint64_t pat = (uint64_t)k * 0x5555555555555555ULL;
  const int gr0 = slab * 32 - 2;      // first loaded row (may be <0)
  for (int wi = tid; wi < 36 * 16; wi += 256) {
    const int gr = gr0 + (wi >> 4);
    uint32_t m = 0;
    if (gr >= 0 && gr < HH)
      m = unpack32(p64[(int64_t)sn * WPI + (gr << 4) + (wi & 15)] ^ pat);
    sfg[wi] = m;
  }
  __syncthreads();

  uint32_t lbest = 0;
  for (int idx = tid; idx < 512; idx += 256) {    // 2 words per thread
    const int rl = 2 + (idx >> 4);                // local row in LDS
    const int col = idx & 15;
    const uint32_t cw = sfg[(rl << 4) + col];
    if (!cw) continue;
    uint64_t rb[5];
#pragma unroll
    for (int d = 0; d < 5; ++d) {
      const int base = ((rl + d - 2) << 4) + col;
      const uint32_t le = (col > 0)  ? sfg[base - 1] : 0u;
      const uint32_t cu = sfg[base];
      const uint32_t ri = (col < 15) ? sfg[base + 1] : 0u;
      rb[d] = ((uint64_t)(ri & 7u) << 34) | ((uint64_t)cu << 2) | (uint64_t)(le >> 30);
    }
    const int gr = slab * 32 + (idx >> 4);
    uint32_t bits = cw;
    while (bits) {
      const int j = __ffs(bits) - 1;
      bits &= bits - 1;
      int cnt = 0;
#pragma unroll
      for (int d = 0; d < 5; ++d)
        cnt += __popc((uint32_t)(rb[d] >> j) & 0x1fu);
      const uint32_t fidx = (uint32_t)((gr << 9) + (col << 5) + j);
      const uint32_t key = ((uint32_t)cnt << 18) | (0x3FFFFu - fidx);
      lbest = lbest > key ? lbest : key;
    }
  }
#pragma unroll
  for (int off = 32; off > 0; off >>= 1) {
    const uint32_t o = (uint32_t)__shfl_down((int)lbest, off, 64);
    lbest = lbest > o ? lbest : o;
  }
  if ((threadIdx.x & 63) == 0 && lbest) atomicMax(&skey, lbest);
  __syncthreads();
  if (tid == 0 && skey) atomicMax(&gkey[prob], skey);
}

// ---- BFS fallback helpers (validated in R2) ----

__device__ __forceinline__ uint32_t runmask(uint32_t m, uint32_t s) {
  uint32_t out = 0;
  while (s) {
    const int j = __ffs(s) - 1;
    const uint32_t bj = 1u << j;
    const uint32_t up = ((m + bj) ^ m) & m;
    const uint32_t rm = __brev(m);
    const uint32_t rbj = 1u << (31 - j);
    const uint32_t dn = __brev(((rm + rbj) ^ rm) & rm);
    const uint32_t run = up | dn;
    out |= run;
    s &= ~run;
  }
  return out;
}

__device__ __forceinline__ void claimf(uint32_t* fg, uint32_t* qw, uint32_t* qb,
                                       uint32_t* qtail, uint32_t t, uint32_t want) {
  const uint32_t old = atomicAnd(&fg[t], ~want);
  uint32_t nb = old & want;
  if (!nb) return;
  const uint32_t ext = runmask(old, nb) & ~nb;
  if (ext) {
    const uint32_t old2 = atomicAnd(&fg[t], ~ext);
    nb |= old2 & ext;
  }
  const uint32_t slot = atomicAdd(qtail, 1u);
  if (slot < QCAP) { qw[slot] = t; qb[slot] = nb; }
}

__device__ __forceinline__ uint64_t shup64(uint64_t v) {
  const uint32_t lo = __shfl_up((unsigned int)v, 1, 64);
  const uint32_t hi = __shfl_up((unsigned int)(v >> 32), 1, 64);
  return ((uint64_t)hi << 32) | lo;
}
__device__ __forceinline__ uint64_t shdn64(uint64_t v) {
  const uint32_t lo = __shfl_down((unsigned int)v, 1, 64);
  const uint32_t hi = __shfl_down((unsigned int)(v >> 32), 1, 64);
  return ((uint64_t)hi << 32) | lo;
}

// ---------------- Kernel B2: windowed flood fill + reward sum ----------------
// 120 blocks x 64 threads (one wave). Common path never touches LDS.
__global__ __launch_bounds__(64) void k_fill(const float* __restrict__ preds,
                                             const uint8_t* __restrict__ packed,
                                             const uint32_t* __restrict__ gkey,
                                             float* __restrict__ acc) {
  __shared__ uint32_t fg[WPI];     // fallback only
  __shared__ uint32_t qw[QCAP];
  __shared__ uint32_t qb[QCAP];
  __shared__ uint32_t qtail;
  const int tid = threadIdx.x;     // 0..63
  const int prob = blockIdx.x;
  const int sn = prob % 40;
  const int k  = 1 + prob / 40;
  const int n  = sn & 3;

  const uint32_t bkey = gkey[prob];
  if ((bkey >> 18) == 0u) return;           // no fg -> reward 0

  const uint32_t seed = 0x3FFFFu - (bkey & 0x3FFFFu);
  const int sr = (int)(seed >> 9), sc = (int)(seed & 511);
  const float* chan = preds + (((int64_t)n) * NCLS + k) * (int64_t)IMG;
  const uint64_t* p64 = reinterpret_cast<const uint64_t*>(packed);
  const uint64_t pat = (uint64_t)k * 0x5555555555555555ULL;
  float local = 0.0f;

  // ---- windowed register flood fill: 64 rows x 64 cols around the seed ----
  int r0 = sr - 31; if (r0 < 0) r0 = 0; if (r0 > HH - 64) r0 = HH - 64;
  int cl = (sc >> 5) - (((sc & 31) < 16) ? 1 : 0);
  if (cl < 0) cl = 0; if (cl > 14) cl = 14;
  const int ar = r0 + tid;                  // this lane's absolute row
  const int64_t pb = (int64_t)sn * WPI + (ar << 4) + cl;
  const uint64_t fgw = ((uint64_t)unpack32(p64[pb + 1] ^ pat) << 32)
                     |            unpack32(p64[pb]     ^ pat);
  uint64_t fill = (ar == sr) ? (1ULL << (sc - (cl << 5))) : 0ULL;

  bool conv = false;
  for (int it = 0; it < 2048; ++it) {
    uint64_t up = shup64(fill); if (tid == 0)  up = 0ULL;
    uint64_t dn = shdn64(fill); if (tid == 63) dn = 0ULL;
    const uint64_t sp = fill | up | dn;
    const uint64_t nf = (fgw & (sp | (sp << 1) | (sp >> 1))) | fill;
    const bool ch = (nf != fill);
    fill = nf;
    if (__ballot(ch) == 0ULL) { conv = true; break; }
  }

  bool esc = !conv;
  if (fill) {
    if (tid == 0 && r0 > 0) esc = true;
    if (tid == 63 && r0 + 63 < HH - 1) esc = true;
    if ((fill & 1ULL) && cl > 0) esc = true;
    if ((fill >> 63) && cl < 14) esc = true;
  }

  if (__ballot(esc) == 0ULL) {
    uint64_t bits = fill;
    const float* rowp = chan + (int64_t)ar * WW + (cl << 5);
    while (bits) {
      const int j = __ffsll((unsigned long long)bits) - 1;
      bits &= bits - 1;
      local += logf(rowp[j] + 1e-16f);
    }
  } else {
    // ---- rare fallback: build full fg in LDS, exact word-level BFS ----
    if (tid == 0) qtail = 0u;
    for (int wi = tid; wi < WPI; wi += 64)
      fg[wi] = unpack32(p64[(int64_t)sn * WPI + wi] ^ pat);
    __syncthreads();
    claimf(fg, qw, qb, &qtail, seed >> 5, 1u << (seed & 31));
    uint32_t head = 0;
    while (true) {
      uint32_t tail = atomicAdd(&qtail, 0u);
      if (tail > QCAP) tail = QCAP;
      if (head >= tail) break;
      for (uint32_t i = head + (uint32_t)tid; i < tail; i += 64) {
        const uint32_t w = qw[i], got = qb[i];
        const int row = (int)(w >> 4), cb = (int)(w & 15);
        const uint32_t spread = got | (got << 1) | (got >> 1);
        const bool lo = (got & 1u) != 0u, hi = (got >> 31) != 0u;
        if (row > 0) {
          claimf(fg, qw, qb, &qtail, w - 16, spread);
          if (cb > 0 && lo)  claimf(fg, qw, qb, &qtail, w - 17, 0x80000000u);
          if (cb < 15 && hi) claimf(fg, qw, qb, &qtail, w - 15, 1u);
        }
        if (row < HH - 1) {
          claimf(fg, qw, qb, &qtail, w + 16, spread);
          if (cb > 0 && lo)  claimf(fg, qw, qb, &qtail, w + 15, 0x80000000u);
          if (cb < 15 && hi) claimf(fg, qw, qb, &qtail, w + 17, 1u);
        }
        if (cb > 0 && lo)  claimf(fg, qw, qb, &qtail, w - 1, 0x80000000u);
        if (cb < 15 && hi) claimf(fg, qw, qb, &qtail, w + 1, 1u);
      }
      head = tail;
    }
    uint32_t tot = qtail; if (tot > QCAP) tot = QCAP;
    for (uint32_t i = (uint32_t)tid; i < tot; i += 64) {
      const uint32_t w = qw[i];
      uint32_t bits = qb[i];
      const int row = (int)(w >> 4);
      const int colb = (int)(w & 15) << 5;
      const float* rowp = chan + (int64_t)row * WW;
      while (bits) {
        const int j = __ffs(bits) - 1;
        bits &= bits - 1;
        local += logf(rowp[colb + j] + 1e-16f);
      }
    }
  }

#pragma unroll
  for (int off = 32; off > 0; off >>= 1)
    local += __shfl_down(local, off, 64);
  if (tid == 0 && local != 0.0f)
    atomicAdd(acc, local);
}

// ---------------- Kernel C: finalize ----------------
__global__ void k_final(const float* __restrict__ acc, float* __restrict__ out) {
  out[0] = -acc[0] / 10485760.0f;
}

extern "C" void kernel_launch(void* const* d_in, const int* in_sizes, int n_in,
                              void* d_out, int out_size, void* d_ws, size_t ws_size,
                              hipStream_t stream) {
  const float* preds = (const float*)d_in[0];
  float* out = (float*)d_out;
  // ws layout: [0..3] float acc | [64..543] 120 u32 argmax keys | [4096..] packed classes
  float* acc = (float*)d_ws;
  uint32_t* gkey = (uint32_t*)((char*)d_ws + 64);
  uint8_t* packed = (uint8_t*)d_ws + 4096;

  k_sample<<<10240, 256, 0, stream>>>(preds, packed, acc, gkey);  // 2,621,440 threads
  k_argmax<<<1920, 256, 0, stream>>>(packed, gkey);
  k_fill<<<120, 64, 0, stream>>>(preds, packed, gkey, acc);
  k_final<<<1, 1, 0, stream>>>(acc, out);
}